// Round 6
// baseline (702.825 us; speedup 1.0000x reference)
//
#include <hip/hip_runtime.h>

typedef unsigned short u16;
typedef unsigned int u32;

// workspace offsets (in floats)
#define STATSP 2048     // 16*12*64*2 = 24576 floats of stats partials
#define CTROFF 26624    // 1 int: grid-barrier counter for k_chain
#define KKOFF0 591872
#define KKOFF1 616448
#define KKOFF2 665600
#define WOFF 763904
#define R0OFF 5482496
#define R1OFF 6072320
#define R2OFF 7251968
#define HTOTOFF 11675648
// total = 11712512 floats = ~46.9 MB
// fp64 chain scratch lives INSIDE the Wtil region [WOFF, R0OFF); it is fully
// consumed by k_chain's final phase before k_s3 overwrites Wtil. Offsets in
// doubles relative to (double*)(ws + WOFF):
#define AD64 0        // 3*65536 doubles  (Ad fp64, per scale)
#define PD64 196608   // 6*65536 doubles  (P ping-pong, per scale)
#define KKD64 589824  // 672*256 doubles  (KK rows: s0 96, s1 192, s2 384)

#define NBLK 256      // k_chain grid (must all be co-resident: 17KB LDS -> ~9 blk/CU cap)

// ---- convert A (f32) -> fp64, Bv -> fp64 KK row 0 per scale; zero barrier ctr ----
__global__ __launch_bounds__(256) void k_convert(const float* __restrict__ Ab,
                                                 const float* __restrict__ Bb,
                                                 float* __restrict__ ws) {
  double* dws = (double*)(ws + WOFF);
  int idx = blockIdx.x * 256 + threadIdx.x;
  if (idx == 0) *(int*)(ws + CTROFF) = 0;
  if (idx < 196608) {
    dws[AD64 + idx] = (double)Ab[idx];
  } else {
    int g = idx - 196608;
    if (g < 768) {
      const int rowoff[3] = {0, 24576, 73728};
      int s = g >> 8, i = g & 255;
      dws[KKD64 + rowoff[s] + i] = (double)Bb[g];
    }
  }
}

// ---- stats phase 1: partial sum/sumsq per (b, lpart, j) ----
__global__ __launch_bounds__(256) void k_stats1(const float* __restrict__ xin, float* __restrict__ ws) {
  int blk = blockIdx.x;         // b*12 + part
  int b = blk / 12, part = blk % 12;
  int tid = threadIdx.x;
  int j = tid & 63, g = tid >> 6;  // g in 0..3
  const float* xp = xin + ((size_t)b * 720 + part * 60 + g) * 64 + j;
  float sum = 0.f, ss = 0.f;
#pragma unroll
  for (int i = 0; i < 15; ++i) {
    float v = xp[(size_t)i * 256];
    sum += v; ss += v * v;
  }
  __shared__ float rs[4][64], rq[4][64];
  rs[g][j] = sum; rq[g][j] = ss;
  __syncthreads();
  if (g == 0) {
    float s = rs[0][j] + rs[1][j] + rs[2][j] + rs[3][j];
    float q = rq[0][j] + rq[1][j] + rq[2][j] + rq[3][j];
    float* dst = ws + STATSP + ((size_t)blk * 64 + j) * 2;
    dst[0] = s; dst[1] = q;
  }
}

// ---- persistent chain kernel: all 9 doubling rounds + d2f + Htot zero ----
// 32x32 tiles / 2x2 micro (LDS-BW-optimal for tiny-matrix rounds), grid barrier
// between rounds via device-scope atomic counter (all NBLK blocks co-resident).
__global__ __launch_bounds__(256) void k_chain(float* __restrict__ ws) {
  double* base = (double*)(ws + WOFF);
  const double* AD = base + AD64;
  double* PD = base + PD64;
  double* KD = base + KKD64;
  int* ctr = (int*)(ws + CTROFF);
  const int Ts[3] = {96, 192, 384};
  const int rowoff[3] = {0, 24576, 73728};
  __shared__ double As[32][33], Bs[32][33];
  int have[3] = {1, 1, 1};
  int target = 0;
  for (int r = 0; r <= 8; ++r) {
    // build this round's job list (identical on every block)
    const double* JA[6]; const double* JB[6]; double* JC[6];
    int JM[6], JT[6], T0[7];
    int nj = 0, tiles = 0;
    T0[0] = 0;
    for (int s = 0; s < 3; ++s) {
      int T = Ts[s];
      if (have[s] >= T) continue;
      const double* Pn = (r == 0) ? (AD + (size_t)s * 65536)
                                  : (PD + (size_t)(2 * s + (r & 1)) * 65536);
      int M = ((2 * have[s] < T) ? 2 * have[s] : T) - have[s];
      JA[nj] = KD + rowoff[s]; JB[nj] = Pn;
      JC[nj] = KD + rowoff[s] + (size_t)have[s] * 256;
      JM[nj] = M; JT[nj] = 1; tiles += ((M + 31) / 32) * 8; nj++; T0[nj] = tiles;
      if (2 * have[s] < T) {
        JA[nj] = Pn; JB[nj] = Pn;
        JC[nj] = PD + (size_t)(2 * s + ((r + 1) & 1)) * 65536;
        JM[nj] = 256; JT[nj] = 0; tiles += 64; nj++; T0[nj] = tiles;
      }
      have[s] = (2 * have[s] < T) ? 2 * have[s] : T;
    }
    for (int tile = blockIdx.x; tile < tiles; tile += NBLK) {
      int j = 0;
      for (int q = 1; q < nj; ++q) if (tile >= T0[q]) j = q;
      int local = tile - T0[j];
      int tm = local >> 3, tn = local & 7;
      const double* A = JA[j]; const double* Bm = JB[j]; double* C = JC[j];
      int M = JM[j], tB = JT[j];
      int row0 = tm * 32, col0 = tn * 32;
      int tid = threadIdx.x, ty = tid >> 4, tx = tid & 15;
      double a00 = 0., a01 = 0., a10 = 0., a11 = 0.;
      int lr = tid >> 3, lk = (tid & 7) << 2;
      for (int kc = 0; kc < 256; kc += 32) {
#pragma unroll
        for (int u = 0; u < 4; ++u) {
          As[lr][lk + u] = (row0 + lr < M) ? A[(size_t)(row0 + lr) * 256 + kc + lk + u] : 0.0;
          if (tB) Bs[lk + u][lr] = Bm[(size_t)(col0 + lr) * 256 + kc + lk + u];
          else    Bs[lr][lk + u] = Bm[(size_t)(kc + lr) * 256 + col0 + lk + u];
        }
        __syncthreads();
#pragma unroll 8
        for (int k = 0; k < 32; ++k) {
          double x0 = As[2 * ty][k], x1 = As[2 * ty + 1][k];
          double y0 = Bs[k][2 * tx], y1 = Bs[k][2 * tx + 1];
          a00 = fma(x0, y0, a00); a01 = fma(x0, y1, a01);
          a10 = fma(x1, y0, a10); a11 = fma(x1, y1, a11);
        }
        __syncthreads();
      }
      int r0i = row0 + 2 * ty, c0i = col0 + 2 * tx;
      if (r0i < M) { C[(size_t)r0i * 256 + c0i] = a00; C[(size_t)r0i * 256 + c0i + 1] = a01; }
      if (r0i + 1 < M) { C[(size_t)(r0i + 1) * 256 + c0i] = a10; C[(size_t)(r0i + 1) * 256 + c0i + 1] = a11; }
    }
    // ---- grid barrier ----
    __syncthreads();
    if (threadIdx.x == 0) {
      __threadfence();
      __hip_atomic_fetch_add(ctr, 1, __ATOMIC_ACQ_REL, __HIP_MEMORY_SCOPE_AGENT);
      target += NBLK;
      while (__hip_atomic_load(ctr, __ATOMIC_ACQUIRE, __HIP_MEMORY_SCOPE_AGENT) < target) {
        __builtin_amdgcn_s_sleep(2);
      }
      __threadfence();
    }
    __syncthreads();
  }
  // ---- final phase: KK fp64 -> fp32; zero Htot accumulator ----
  int g0 = blockIdx.x * 256 + threadIdx.x;
  for (int idx = g0; idx < 172032; idx += NBLK * 256) {
    float v = (float)KD[idx];
    if (idx < 24576) ws[KKOFF0 + idx] = v;
    else if (idx < 73728) ws[KKOFF1 + idx - 24576] = v;
    else ws[KKOFF2 + idx - 73728] = v;
  }
  for (int idx = g0; idx < 36864; idx += NBLK * 256) ws[HTOTOFF + idx] = 0.f;
}

// ---- S3: Wtil[i,x,t] = sum_o w[i,o,x]*E[t,o]  (per scale, re/im parts) ----
__global__ __launch_bounds__(256) void k_s3(const float* __restrict__ wr, const float* __restrict__ wi,
                                            const float* __restrict__ ev, float* __restrict__ ws) {
  int bid = blockIdx.x;
  int s = bid >> 8;
  int rem = bid & 255;
  int p = rem >> 7;
  int rt = rem & 127;
  const float* w = (p ? wi : wr) + (size_t)s * 2097152;  // 256*256*32
  const float* E = ev + s * 24576;                       // 96*256
  float* C = ws + WOFF + (size_t)(s * 2 + p) * 786432 + rt * 64 * 96;
  int i0 = rt * 2;
  __shared__ float Ws[32][68];   // [o][i_local*32+x]
  __shared__ float Es[32][102];  // [o][t]  (stride 102: staging writes 2-way = free)
  int tid = threadIdx.x;
  int ty = tid >> 4, tx = tid & 15;
  float acc[4][6];
#pragma unroll
  for (int u = 0; u < 4; ++u)
#pragma unroll
    for (int v = 0; v < 6; ++v) acc[u][v] = 0.f;
  for (int ko = 0; ko < 256; ko += 32) {
    {
      int g = tid * 8;
      int il = g >> 10;
      int r2 = g & 1023;
      int o = r2 >> 5, x = r2 & 31;
      const float* src = w + ((size_t)(i0 + il) * 256 + ko + o) * 32 + x;
      float4 v0 = *(const float4*)src;
      float4 v1 = *(const float4*)(src + 4);
      int dst = il * 32 + x;
      *(float4*)&Ws[o][dst] = v0;
      *(float4*)&Ws[o][dst + 4] = v1;
    }
    for (int idx = tid; idx < 384; idx += 256) {
      int t = idx >> 2;
      int oo = (idx & 3) << 3;
      const float* src = E + t * 256 + ko + oo;
      float4 v0 = *(const float4*)src;
      float4 v1 = *(const float4*)(src + 4);
      Es[oo + 0][t] = v0.x; Es[oo + 1][t] = v0.y; Es[oo + 2][t] = v0.z; Es[oo + 3][t] = v0.w;
      Es[oo + 4][t] = v1.x; Es[oo + 5][t] = v1.y; Es[oo + 6][t] = v1.z; Es[oo + 7][t] = v1.w;
    }
    __syncthreads();
#pragma unroll 4
    for (int k = 0; k < 32; ++k) {
      float4 a = *(const float4*)&Ws[k][ty * 4];
      float2 b0 = *(const float2*)&Es[k][tx * 6];
      float2 b1 = *(const float2*)&Es[k][tx * 6 + 2];
      float2 b2 = *(const float2*)&Es[k][tx * 6 + 4];
      float aa[4] = {a.x, a.y, a.z, a.w};
      float bb[6] = {b0.x, b0.y, b1.x, b1.y, b2.x, b2.y};
#pragma unroll
      for (int u = 0; u < 4; ++u)
#pragma unroll
        for (int v = 0; v < 6; ++v) acc[u][v] += aa[u] * bb[v];
    }
    __syncthreads();
  }
#pragma unroll
  for (int u = 0; u < 4; ++u) {
    int row = ty * 4 + u;
    float* cp = C + row * 96 + tx * 6;
    cp[0] = acc[u][0]; cp[1] = acc[u][1]; cp[2] = acc[u][2];
    cp[3] = acc[u][3]; cp[4] = acc[u][4]; cp[5] = acc[u][5];
  }
}

// ---- S4: R[d,(x,t)] = sum_i KK[d,i]*Wtil[i,(x,t)]   64x64 tiles, K=256 ----
__global__ __launch_bounds__(256) void k_s4(float* __restrict__ ws) {
  int bid = blockIdx.x;
  const int cums[6] = {0, 96, 192, 336, 480, 768};
  int jidx = 0;
  for (int q = 1; q < 6; ++q) if (bid >= cums[q]) jidx = q;
  int local = bid - cums[jidx];
  int s = jidx >> 1, p = jidx & 1;
  const int Ts[3] = {96, 192, 384};
  const int KKo[3] = {KKOFF0, KKOFF1, KKOFF2};
  const int Ro[3] = {R0OFF, R1OFF, R2OFF};
  int T = Ts[s];
  int tm = local / 48, tn = local % 48;
  int row0 = tm * 64, col0 = tn * 64;
  const float* A = ws + KKo[s];
  const float* B = ws + WOFF + (size_t)(2 * s + p) * 786432;
  float* C = ws + Ro[s] + (size_t)p * T * 3072;
  __shared__ float As[32][68], Bs[32][68];  // [k][row], [k][col]
  int tid = threadIdx.x;
  int ty = tid >> 4, tx = tid & 15;
  float acc[4][4];
#pragma unroll
  for (int u = 0; u < 4; ++u)
#pragma unroll
    for (int v = 0; v < 4; ++v) acc[u][v] = 0.f;
  for (int kc = 0; kc < 256; kc += 32) {
    int r = tid >> 2, k8 = (tid & 3) << 3;
    if (row0 + r < T) {
      float4 v0 = *(const float4*)(A + (size_t)(row0 + r) * 256 + kc + k8);
      float4 v1 = *(const float4*)(A + (size_t)(row0 + r) * 256 + kc + k8 + 4);
      As[k8 + 0][r] = v0.x; As[k8 + 1][r] = v0.y; As[k8 + 2][r] = v0.z; As[k8 + 3][r] = v0.w;
      As[k8 + 4][r] = v1.x; As[k8 + 5][r] = v1.y; As[k8 + 6][r] = v1.z; As[k8 + 7][r] = v1.w;
    } else {
#pragma unroll
      for (int u = 0; u < 8; ++u) As[k8 + u][r] = 0.f;
    }
    int kr = tid >> 3, c8 = (tid & 7) << 3;
    const float* bp = B + (size_t)(kc + kr) * 3072 + col0 + c8;
    *(float4*)&Bs[kr][c8] = *(const float4*)bp;
    *(float4*)&Bs[kr][c8 + 4] = *(const float4*)(bp + 4);
    __syncthreads();
#pragma unroll 8
    for (int k = 0; k < 32; ++k) {
      float4 a = *(const float4*)&As[k][ty * 4];
      float4 b = *(const float4*)&Bs[k][tx * 4];
      float aa[4] = {a.x, a.y, a.z, a.w};
      float bb[4] = {b.x, b.y, b.z, b.w};
#pragma unroll
      for (int u = 0; u < 4; ++u)
#pragma unroll
        for (int v = 0; v < 4; ++v) acc[u][v] += aa[u] * bb[v];
    }
    __syncthreads();
  }
#pragma unroll
  for (int u = 0; u < 4; ++u) {
    int rr = row0 + ty * 4 + u;
    if (rr < T) {
      float* cp = C + (size_t)rr * 3072 + col0 + tx * 4;
      *(float4*)cp = make_float4(acc[u][0], acc[u][1], acc[u][2], acc[u][3]);
    }
  }
}

// ---- S5a: prefix-DFT over d + irfft phase, accumulate w_s * val into Htot ----
// Chunked parallel scan: block = (s, x, t-quarter); 192 threads = 8 chunks x 24 t.
__global__ __launch_bounds__(192) void k_s5a(const float* __restrict__ mlpw, float* __restrict__ ws) {
  int bid = blockIdx.x;
  int s = bid >> 7;
  int rem = bid & 127;
  int x = rem >> 2;
  int tq = rem & 3;
  const int Ts[3] = {96, 192, 384};
  const int Ro[3] = {R0OFF, R1OFF, R2OFF};
  const int lpbase[3] = {288, 192, 0};
  int T = Ts[s];
  int Lc = T >> 3;  // chunk length: 12/24/48
  __shared__ float cs[384][2];
  __shared__ float Lsr[8][24], Lsi[8][24];
  int tid = threadIdx.x;
  for (int e = tid; e < T; e += 192) {
    float th = 6.283185307179586f * (float)e / (float)T;
    cs[e][0] = cosf(th);
    cs[e][1] = sinf(th);
  }
  int c = tid / 24, tl = tid % 24;
  int t = tq * 24 + tl;
  const float* Rre = ws + Ro[s] + (size_t)x * 96 + t;
  const float* Rim = Rre + (size_t)T * 3072;
  float* Htot = ws + HTOTOFF;
  float wsc = mlpw[s];
  __syncthreads();
  int d0 = c * Lc;
  // phase 1: chunk-local twiddle sums
  float zr = 0.f, zi = 0.f;
  for (int d = d0; d < d0 + Lc; ++d) {
    float rr = Rre[(size_t)d * 3072];
    float ri = Rim[(size_t)d * 3072];
    int e1 = (x * d) % T;
    float c1 = cs[e1][0], s1 = cs[e1][1];
    zr += c1 * rr + s1 * ri;
    zi += c1 * ri - s1 * rr;
  }
  Lsr[c][tl] = zr; Lsi[c][tl] = zi;
  __syncthreads();
  // phase 2: exclusive scan over chunks
  if (c == 0) {
    float pr = 0.f, pi = 0.f;
#pragma unroll
    for (int cc = 0; cc < 8; ++cc) {
      float lr = Lsr[cc][tl], li = Lsi[cc][tl];
      Lsr[cc][tl] = pr; Lsi[cc][tl] = pi;
      pr += lr; pi += li;
    }
  }
  __syncthreads();
  // phase 3: replay chunk with running prefix, accumulate into Htot
  zr = Lsr[c][tl]; zi = Lsi[c][tl];
  float sc = (((x == 0) ? 1.f : 2.f) / (float)T) * wsc;
  for (int d = d0; d < d0 + Lc; ++d) {
    float rr = Rre[(size_t)d * 3072];
    float ri = Rim[(size_t)d * 3072];
    int e1 = (x * d) % T;
    float c1 = cs[e1][0], s1 = cs[e1][1];
    zr += c1 * rr + s1 * ri;
    zi += c1 * ri - s1 * rr;
    int k = T - 1 - d;
    int e2 = (x * (95 - k)) % T;
    if (e2 < 0) e2 += T;
    float c2 = cs[e2][0], s2 = cs[e2][1];
    atomicAdd(Htot + (size_t)(lpbase[s] + k) * 96 + t, sc * (c2 * zr - s2 * zi));
  }
}

// ---- S6: out[b,t,j] = sum_l x*Htot + mean*(1-S[t]) + std*mlp_b (stats fused) ----
__global__ __launch_bounds__(256) void k_s6(const float* __restrict__ xin, const float* __restrict__ mlpb_p,
                                            const float* __restrict__ ws, float* __restrict__ out) {
  int b = blockIdx.x >> 2, tq = blockIdx.x & 3;
  int tid = threadIdx.x;
  int j = tid & 63, tsub = tid >> 6;
  __shared__ float Ht[384 * 24];
  for (int idx = tid; idx < 384 * 24; idx += 256) {
    int lp = idx / 24, c = idx % 24;
    Ht[idx] = ws[HTOTOFF + lp * 96 + tq * 24 + c];
  }
  // fused stats reduce: mean/std per (b,j) from 12 partials
  float ssum = 0.f, sq = 0.f;
#pragma unroll
  for (int p = 0; p < 12; ++p) {
    const float* src = ws + STATSP + (((size_t)b * 12 + p) * 64 + j) * 2;
    ssum += src[0]; sq += src[1];
  }
  float mn = ssum * (1.f / 720.f);
  float var = sq * (1.f / 720.f) - mn * mn;
  float sd = sqrtf(var + 1e-5f);
  __syncthreads();
  float mlpb = mlpb_p[0];
  float acc[6] = {0.f, 0.f, 0.f, 0.f, 0.f, 0.f};
  float accS[6] = {0.f, 0.f, 0.f, 0.f, 0.f, 0.f};
  const float* xp = xin + ((size_t)b * 720 + 336) * 64 + j;
  for (int lp = 0; lp < 384; ++lp) {
    float xv = xp[(size_t)lp * 64];
    const float* hr = &Ht[lp * 24 + tsub * 6];
    float2 h01 = *(const float2*)&hr[0];
    float2 h23 = *(const float2*)&hr[2];
    float2 h45 = *(const float2*)&hr[4];
    float hh[6] = {h01.x, h01.y, h23.x, h23.y, h45.x, h45.y};
#pragma unroll
    for (int u = 0; u < 6; ++u) {
      acc[u] += xv * hh[u];
      accS[u] += hh[u];
    }
  }
#pragma unroll
  for (int u = 0; u < 6; ++u) {
    int t = tq * 24 + tsub * 6 + u;
    float val = acc[u] + mn * (1.f - accS[u]) + sd * mlpb;
    out[((size_t)b * 96 + t) * 64 + j] = val;
  }
}

extern "C" void kernel_launch(void* const* d_in, const int* in_sizes, int n_in,
                              void* d_out, int out_size, void* d_ws, size_t ws_size,
                              hipStream_t stream) {
  const float* x  = (const float*)d_in[0];
  const float* wr = (const float*)d_in[1];
  const float* wi = (const float*)d_in[2];
  const float* mw = (const float*)d_in[3];
  const float* mb = (const float*)d_in[4];
  const float* Ab = (const float*)d_in[5];
  const float* Bb = (const float*)d_in[6];
  const float* ev = (const float*)d_in[7];
  float* wsf = (float*)d_ws;
  float* out = (float*)d_out;

  k_convert<<<771, 256, 0, stream>>>(Ab, Bb, wsf);
  k_stats1<<<192, 256, 0, stream>>>(x, wsf);
  k_chain<<<NBLK, 256, 0, stream>>>(wsf);
  k_s3<<<768, 256, 0, stream>>>(wr, wi, ev, wsf);
  k_s4<<<1056, 256, 0, stream>>>(wsf);
  k_s5a<<<384, 192, 0, stream>>>(mw, wsf);
  k_s6<<<64, 256, 0, stream>>>(x, mb, wsf, out);
}

// Round 7
// 394.128 us; speedup vs baseline: 1.7832x; 1.7832x over previous
//
#include <hip/hip_runtime.h>

typedef unsigned short u16;
typedef unsigned int u32;

// workspace offsets (in floats)
#define STATSP 2048     // 16*12*64*2 = 24576 floats of stats partials
#define KKOFF0 591872
#define KKOFF1 616448
#define KKOFF2 665600
#define WOFF 763904
#define R0OFF 5482496
#define R1OFF 6072320
#define R2OFF 7251968
#define HTOTOFF 11675648
// total = 11712512 floats = ~46.9 MB
// fp64 chain scratch lives INSIDE the Wtil region [WOFF, R0OFF); it is fully
// consumed before k_s3 overwrites Wtil. Offsets in doubles relative to
// (double*)(ws + WOFF):
#define AD64 0        // 3*65536 doubles  (Ad fp64, per scale)
#define PD64 196608   // 6*65536 doubles  (P ping-pong, per scale)
#define KKD64 589824  // 672*256 doubles  (KK rows: s0 96, s1 192, s2 384)

// ---- k_pre: convert A->fp64, seed KK row0 (fp64+fp32), stats1, zero Htot ----
__global__ __launch_bounds__(256) void k_pre(const float* __restrict__ Ab,
                                             const float* __restrict__ Bb,
                                             const float* __restrict__ xin,
                                             float* __restrict__ ws) {
  __shared__ float rs[4][64], rq[4][64];
  int blk = blockIdx.x, tid = threadIdx.x;
  if (blk < 771) {
    double* dws = (double*)(ws + WOFF);
    int idx = blk * 256 + tid;
    if (idx < 196608) {
      dws[AD64 + idx] = (double)Ab[idx];
    } else {
      int g = idx - 196608;  // 0..767 (grid sized exactly)
      const int rowoff[3] = {0, 24576, 73728};
      const int kko[3] = {KKOFF0, KKOFF1, KKOFF2};
      int s = g >> 8, i = g & 255;
      float v = Bb[g];
      dws[KKD64 + rowoff[s] + i] = (double)v;
      ws[kko[s] + i] = v;
    }
  } else if (blk < 963) {
    int b2 = blk - 771;  // 0..191
    int b = b2 / 12, part = b2 % 12;
    int j = tid & 63, g = tid >> 6;
    const float* xp = xin + ((size_t)b * 720 + part * 60 + g) * 64 + j;
    float sum = 0.f, ss = 0.f;
#pragma unroll
    for (int i = 0; i < 15; ++i) {
      float v = xp[(size_t)i * 256];
      sum += v; ss += v * v;
    }
    rs[g][j] = sum; rq[g][j] = ss;
    __syncthreads();
    if (g == 0) {
      float s = rs[0][j] + rs[1][j] + rs[2][j] + rs[3][j];
      float q = rq[0][j] + rq[1][j] + rq[2][j] + rq[3][j];
      float* dst = ws + STATSP + ((size_t)b2 * 64 + j) * 2;
      dst[0] = s; dst[1] = q;
    }
  } else {
    int idx = (blk - 963) * 256 + tid;
    for (; idx < 36864; idx += 24 * 256) ws[HTOTOFF + idx] = 0.f;
  }
}

// ---- fp64 chain GEMM, 32x32 tiles, 2x2 micro, K=N=256, register prefetch ----
struct G64Jobs {
  const double* A[8]; const double* B[8]; double* C[8]; float* CF[8];
  int M[8]; int transB[8]; int tile0[8];
  int njobs;
};

__global__ __launch_bounds__(256) void k_gemm64(G64Jobs jb) {
  int bid = blockIdx.x;
  int j = 0;
  for (int q = 1; q < jb.njobs; ++q) if (bid >= jb.tile0[q]) j = q;
  int local = bid - jb.tile0[j];
  int tm = local >> 3, tn = local & 7;
  const double* A = jb.A[j];
  const double* Bm = jb.B[j];
  double* C = jb.C[j];
  float* CF = jb.CF[j];
  int M = jb.M[j], tB = jb.transB[j];
  int row0 = tm * 32, col0 = tn * 32;
  __shared__ double As[32][33], Bs[32][33];
  int tid = threadIdx.x;
  int ty = tid >> 4, tx = tid & 15;
  int lr = tid >> 3, lk = (tid & 7) << 2;
  double va[4], vb[4];
#pragma unroll
  for (int u = 0; u < 4; ++u) {
    va[u] = (row0 + lr < M) ? A[(size_t)(row0 + lr) * 256 + lk + u] : 0.0;
    vb[u] = tB ? Bm[(size_t)(col0 + lr) * 256 + lk + u]
               : Bm[(size_t)lr * 256 + col0 + lk + u];
  }
  double a00 = 0., a01 = 0., a10 = 0., a11 = 0.;
  for (int kc = 0; kc < 256; kc += 32) {
#pragma unroll
    for (int u = 0; u < 4; ++u) {
      As[lr][lk + u] = va[u];
      if (tB) Bs[lk + u][lr] = vb[u];
      else    Bs[lr][lk + u] = vb[u];
    }
    __syncthreads();
    if (kc < 224) {
      int kn = kc + 32;
#pragma unroll
      for (int u = 0; u < 4; ++u) {
        va[u] = (row0 + lr < M) ? A[(size_t)(row0 + lr) * 256 + kn + lk + u] : 0.0;
        vb[u] = tB ? Bm[(size_t)(col0 + lr) * 256 + kn + lk + u]
                   : Bm[(size_t)(kn + lr) * 256 + col0 + lk + u];
      }
    }
#pragma unroll 8
    for (int k = 0; k < 32; ++k) {
      double x0 = As[2 * ty][k], x1 = As[2 * ty + 1][k];
      double y0 = Bs[k][2 * tx], y1 = Bs[k][2 * tx + 1];
      a00 = fma(x0, y0, a00); a01 = fma(x0, y1, a01);
      a10 = fma(x1, y0, a10); a11 = fma(x1, y1, a11);
    }
    __syncthreads();
  }
  int r0 = row0 + 2 * ty, c0 = col0 + 2 * tx;
  if (r0 < M) {
    C[(size_t)r0 * 256 + c0] = a00; C[(size_t)r0 * 256 + c0 + 1] = a01;
    if (CF) { CF[(size_t)r0 * 256 + c0] = (float)a00; CF[(size_t)r0 * 256 + c0 + 1] = (float)a01; }
  }
  if (r0 + 1 < M) {
    C[(size_t)(r0 + 1) * 256 + c0] = a10; C[(size_t)(r0 + 1) * 256 + c0 + 1] = a11;
    if (CF) { CF[(size_t)(r0 + 1) * 256 + c0] = (float)a10; CF[(size_t)(r0 + 1) * 256 + c0 + 1] = (float)a11; }
  }
}

// ---- S3: Wtil[i,x,t] = sum_o w[i,o,x]*E[t,o]  (per scale, re/im parts) ----
__global__ __launch_bounds__(256) void k_s3(const float* __restrict__ wr, const float* __restrict__ wi,
                                            const float* __restrict__ ev, float* __restrict__ ws) {
  int bid = blockIdx.x;
  int s = bid >> 8;
  int rem = bid & 255;
  int p = rem >> 7;
  int rt = rem & 127;
  const float* w = (p ? wi : wr) + (size_t)s * 2097152;  // 256*256*32
  const float* E = ev + s * 24576;                       // 96*256
  float* C = ws + WOFF + (size_t)(s * 2 + p) * 786432 + rt * 64 * 96;
  int i0 = rt * 2;
  __shared__ float Ws[32][68];   // [o][i_local*32+x]
  __shared__ float Es[32][102];  // [o][t]  (stride 102: staging writes 2-way = free)
  int tid = threadIdx.x;
  int ty = tid >> 4, tx = tid & 15;
  float acc[4][6];
#pragma unroll
  for (int u = 0; u < 4; ++u)
#pragma unroll
    for (int v = 0; v < 6; ++v) acc[u][v] = 0.f;
  for (int ko = 0; ko < 256; ko += 32) {
    {
      int g = tid * 8;
      int il = g >> 10;
      int r2 = g & 1023;
      int o = r2 >> 5, x = r2 & 31;
      const float* src = w + ((size_t)(i0 + il) * 256 + ko + o) * 32 + x;
      float4 v0 = *(const float4*)src;
      float4 v1 = *(const float4*)(src + 4);
      int dst = il * 32 + x;
      *(float4*)&Ws[o][dst] = v0;
      *(float4*)&Ws[o][dst + 4] = v1;
    }
    for (int idx = tid; idx < 384; idx += 256) {
      int t = idx >> 2;
      int oo = (idx & 3) << 3;
      const float* src = E + t * 256 + ko + oo;
      float4 v0 = *(const float4*)src;
      float4 v1 = *(const float4*)(src + 4);
      Es[oo + 0][t] = v0.x; Es[oo + 1][t] = v0.y; Es[oo + 2][t] = v0.z; Es[oo + 3][t] = v0.w;
      Es[oo + 4][t] = v1.x; Es[oo + 5][t] = v1.y; Es[oo + 6][t] = v1.z; Es[oo + 7][t] = v1.w;
    }
    __syncthreads();
#pragma unroll 4
    for (int k = 0; k < 32; ++k) {
      float4 a = *(const float4*)&Ws[k][ty * 4];
      float2 b0 = *(const float2*)&Es[k][tx * 6];
      float2 b1 = *(const float2*)&Es[k][tx * 6 + 2];
      float2 b2 = *(const float2*)&Es[k][tx * 6 + 4];
      float aa[4] = {a.x, a.y, a.z, a.w};
      float bb[6] = {b0.x, b0.y, b1.x, b1.y, b2.x, b2.y};
#pragma unroll
      for (int u = 0; u < 4; ++u)
#pragma unroll
        for (int v = 0; v < 6; ++v) acc[u][v] += aa[u] * bb[v];
    }
    __syncthreads();
  }
#pragma unroll
  for (int u = 0; u < 4; ++u) {
    int row = ty * 4 + u;
    float* cp = C + row * 96 + tx * 6;
    cp[0] = acc[u][0]; cp[1] = acc[u][1]; cp[2] = acc[u][2];
    cp[3] = acc[u][3]; cp[4] = acc[u][4]; cp[5] = acc[u][5];
  }
}

// ---- S4: R[d,(x,t)] = sum_i KK[d,i]*Wtil[i,(x,t)]   64x64 tiles, K=256 ----
__global__ __launch_bounds__(256) void k_s4(float* __restrict__ ws) {
  int bid = blockIdx.x;
  const int cums[6] = {0, 96, 192, 336, 480, 768};
  int jidx = 0;
  for (int q = 1; q < 6; ++q) if (bid >= cums[q]) jidx = q;
  int local = bid - cums[jidx];
  int s = jidx >> 1, p = jidx & 1;
  const int Ts[3] = {96, 192, 384};
  const int KKo[3] = {KKOFF0, KKOFF1, KKOFF2};
  const int Ro[3] = {R0OFF, R1OFF, R2OFF};
  int T = Ts[s];
  int tm = local / 48, tn = local % 48;
  int row0 = tm * 64, col0 = tn * 64;
  const float* A = ws + KKo[s];
  const float* B = ws + WOFF + (size_t)(2 * s + p) * 786432;
  float* C = ws + Ro[s] + (size_t)p * T * 3072;
  __shared__ float As[32][68], Bs[32][68];  // [k][row], [k][col]
  int tid = threadIdx.x;
  int ty = tid >> 4, tx = tid & 15;
  float acc[4][4];
#pragma unroll
  for (int u = 0; u < 4; ++u)
#pragma unroll
    for (int v = 0; v < 4; ++v) acc[u][v] = 0.f;
  for (int kc = 0; kc < 256; kc += 32) {
    int r = tid >> 2, k8 = (tid & 3) << 3;
    if (row0 + r < T) {
      float4 v0 = *(const float4*)(A + (size_t)(row0 + r) * 256 + kc + k8);
      float4 v1 = *(const float4*)(A + (size_t)(row0 + r) * 256 + kc + k8 + 4);
      As[k8 + 0][r] = v0.x; As[k8 + 1][r] = v0.y; As[k8 + 2][r] = v0.z; As[k8 + 3][r] = v0.w;
      As[k8 + 4][r] = v1.x; As[k8 + 5][r] = v1.y; As[k8 + 6][r] = v1.z; As[k8 + 7][r] = v1.w;
    } else {
#pragma unroll
      for (int u = 0; u < 8; ++u) As[k8 + u][r] = 0.f;
    }
    int kr = tid >> 3, c8 = (tid & 7) << 3;
    const float* bp = B + (size_t)(kc + kr) * 3072 + col0 + c8;
    *(float4*)&Bs[kr][c8] = *(const float4*)bp;
    *(float4*)&Bs[kr][c8 + 4] = *(const float4*)(bp + 4);
    __syncthreads();
#pragma unroll 8
    for (int k = 0; k < 32; ++k) {
      float4 a = *(const float4*)&As[k][ty * 4];
      float4 b = *(const float4*)&Bs[k][tx * 4];
      float aa[4] = {a.x, a.y, a.z, a.w};
      float bb[4] = {b.x, b.y, b.z, b.w};
#pragma unroll
      for (int u = 0; u < 4; ++u)
#pragma unroll
        for (int v = 0; v < 4; ++v) acc[u][v] += aa[u] * bb[v];
    }
    __syncthreads();
  }
#pragma unroll
  for (int u = 0; u < 4; ++u) {
    int rr = row0 + ty * 4 + u;
    if (rr < T) {
      float* cp = C + (size_t)rr * 3072 + col0 + tx * 4;
      *(float4*)cp = make_float4(acc[u][0], acc[u][1], acc[u][2], acc[u][3]);
    }
  }
}

// ---- S5a: prefix-DFT over d + irfft phase, accumulate w_s * val into Htot ----
__global__ __launch_bounds__(192) void k_s5a(const float* __restrict__ mlpw, float* __restrict__ ws) {
  int bid = blockIdx.x;
  int s = bid >> 7;
  int rem = bid & 127;
  int x = rem >> 2;
  int tq = rem & 3;
  const int Ts[3] = {96, 192, 384};
  const int Ro[3] = {R0OFF, R1OFF, R2OFF};
  const int lpbase[3] = {288, 192, 0};
  int T = Ts[s];
  int Lc = T >> 3;
  __shared__ float cs[384][2];
  __shared__ float Lsr[8][24], Lsi[8][24];
  int tid = threadIdx.x;
  for (int e = tid; e < T; e += 192) {
    float th = 6.283185307179586f * (float)e / (float)T;
    cs[e][0] = cosf(th);
    cs[e][1] = sinf(th);
  }
  int c = tid / 24, tl = tid % 24;
  int t = tq * 24 + tl;
  const float* Rre = ws + Ro[s] + (size_t)x * 96 + t;
  const float* Rim = Rre + (size_t)T * 3072;
  float* Htot = ws + HTOTOFF;
  float wsc = mlpw[s];
  __syncthreads();
  int d0 = c * Lc;
  float zr = 0.f, zi = 0.f;
  for (int d = d0; d < d0 + Lc; ++d) {
    float rr = Rre[(size_t)d * 3072];
    float ri = Rim[(size_t)d * 3072];
    int e1 = (x * d) % T;
    float c1 = cs[e1][0], s1 = cs[e1][1];
    zr += c1 * rr + s1 * ri;
    zi += c1 * ri - s1 * rr;
  }
  Lsr[c][tl] = zr; Lsi[c][tl] = zi;
  __syncthreads();
  if (c == 0) {
    float pr = 0.f, pi = 0.f;
#pragma unroll
    for (int cc = 0; cc < 8; ++cc) {
      float lr = Lsr[cc][tl], li = Lsi[cc][tl];
      Lsr[cc][tl] = pr; Lsi[cc][tl] = pi;
      pr += lr; pi += li;
    }
  }
  __syncthreads();
  zr = Lsr[c][tl]; zi = Lsi[c][tl];
  float sc = (((x == 0) ? 1.f : 2.f) / (float)T) * wsc;
  for (int d = d0; d < d0 + Lc; ++d) {
    float rr = Rre[(size_t)d * 3072];
    float ri = Rim[(size_t)d * 3072];
    int e1 = (x * d) % T;
    float c1 = cs[e1][0], s1 = cs[e1][1];
    zr += c1 * rr + s1 * ri;
    zi += c1 * ri - s1 * rr;
    int k = T - 1 - d;
    int e2 = (x * (95 - k)) % T;
    if (e2 < 0) e2 += T;
    float c2 = cs[e2][0], s2 = cs[e2][1];
    atomicAdd(Htot + (size_t)(lpbase[s] + k) * 96 + t, sc * (c2 * zr - s2 * zi));
  }
}

// ---- S6: out[b,t,j] = sum_l x*Htot + mean*(1-S[t]) + std*mlp_b (stats fused) ----
__global__ __launch_bounds__(256) void k_s6(const float* __restrict__ xin, const float* __restrict__ mlpb_p,
                                            const float* __restrict__ ws, float* __restrict__ out) {
  int b = blockIdx.x >> 2, tq = blockIdx.x & 3;
  int tid = threadIdx.x;
  int j = tid & 63, tsub = tid >> 6;
  __shared__ float Ht[384 * 24];
  for (int idx = tid; idx < 384 * 24; idx += 256) {
    int lp = idx / 24, c = idx % 24;
    Ht[idx] = ws[HTOTOFF + lp * 96 + tq * 24 + c];
  }
  float ssum = 0.f, sq = 0.f;
#pragma unroll
  for (int p = 0; p < 12; ++p) {
    const float* src = ws + STATSP + (((size_t)b * 12 + p) * 64 + j) * 2;
    ssum += src[0]; sq += src[1];
  }
  float mn = ssum * (1.f / 720.f);
  float var = sq * (1.f / 720.f) - mn * mn;
  float sd = sqrtf(var + 1e-5f);
  __syncthreads();
  float mlpb = mlpb_p[0];
  float acc[6] = {0.f, 0.f, 0.f, 0.f, 0.f, 0.f};
  float accS[6] = {0.f, 0.f, 0.f, 0.f, 0.f, 0.f};
  const float* xp = xin + ((size_t)b * 720 + 336) * 64 + j;
  for (int lp = 0; lp < 384; ++lp) {
    float xv = xp[(size_t)lp * 64];
    const float* hr = &Ht[lp * 24 + tsub * 6];
    float2 h01 = *(const float2*)&hr[0];
    float2 h23 = *(const float2*)&hr[2];
    float2 h45 = *(const float2*)&hr[4];
    float hh[6] = {h01.x, h01.y, h23.x, h23.y, h45.x, h45.y};
#pragma unroll
    for (int u = 0; u < 6; ++u) {
      acc[u] += xv * hh[u];
      accS[u] += hh[u];
    }
  }
#pragma unroll
  for (int u = 0; u < 6; ++u) {
    int t = tq * 24 + tsub * 6 + u;
    float val = acc[u] + mn * (1.f - accS[u]) + sd * mlpb;
    out[((size_t)b * 96 + t) * 64 + j] = val;
  }
}

extern "C" void kernel_launch(void* const* d_in, const int* in_sizes, int n_in,
                              void* d_out, int out_size, void* d_ws, size_t ws_size,
                              hipStream_t stream) {
  const float* x  = (const float*)d_in[0];
  const float* wr = (const float*)d_in[1];
  const float* wi = (const float*)d_in[2];
  const float* mw = (const float*)d_in[3];
  const float* mb = (const float*)d_in[4];
  const float* Ab = (const float*)d_in[5];
  const float* Bb = (const float*)d_in[6];
  const float* ev = (const float*)d_in[7];
  float* wsf = (float*)d_ws;
  float* out = (float*)d_out;

  k_pre<<<987, 256, 0, stream>>>(Ab, Bb, x, wsf);

  const double* AD = (const double*)(wsf + WOFF) + AD64;
  double* PD = (double*)(wsf + WOFF) + PD64;
  double* KD = (double*)(wsf + WOFF) + KKD64;
  static const int Ts[3] = {96, 192, 384};
  static const int rowoff[3] = {0, 24576, 73728};
  static const int KKo[3] = {KKOFF0, KKOFF1, KKOFF2};

  // Fused doubling: round r extends KK rows [n, min(2n,T)) = KK[0,n) * P_n^T
  // (dual-written fp64+fp32) and squares P_n -> P_2n in the same launch.
  int have[3] = {1, 1, 1};
  for (int r = 0; r <= 8; ++r) {
    G64Jobs jb;
    jb.njobs = 0;
    int tiles = 0;
    for (int s = 0; s < 3; ++s) {
      int T = Ts[s];
      if (have[s] >= T) continue;
      const double* Pn = (r == 0) ? (AD + (size_t)s * 65536)
                                  : (PD + (size_t)(2 * s + (r & 1)) * 65536);
      int M = ((2 * have[s] < T) ? 2 * have[s] : T) - have[s];
      int q = jb.njobs++;
      jb.A[q] = KD + rowoff[s]; jb.B[q] = Pn;
      jb.C[q] = KD + rowoff[s] + (size_t)have[s] * 256;
      jb.CF[q] = wsf + KKo[s] + (size_t)have[s] * 256;
      jb.M[q] = M; jb.transB[q] = 1; jb.tile0[q] = tiles;
      tiles += ((M + 31) / 32) * 8;
      if (2 * have[s] < T) {
        q = jb.njobs++;
        jb.A[q] = Pn; jb.B[q] = Pn;
        jb.C[q] = PD + (size_t)(2 * s + ((r + 1) & 1)) * 65536;
        jb.CF[q] = nullptr;
        jb.M[q] = 256; jb.transB[q] = 0; jb.tile0[q] = tiles;
        tiles += 64;
      }
      have[s] = (2 * have[s] < T) ? 2 * have[s] : T;
    }
    if (jb.njobs) k_gemm64<<<tiles, 256, 0, stream>>>(jb);
  }

  k_s3<<<768, 256, 0, stream>>>(wr, wi, ev, wsf);
  k_s4<<<1056, 256, 0, stream>>>(wsf);
  k_s5a<<<384, 192, 0, stream>>>(mw, wsf);
  k_s6<<<64, 256, 0, stream>>>(x, mb, wsf, out);
}